// Round 10
// baseline (8170.956 us; speedup 1.0000x reference)
//
#include <hip/hip_runtime.h>
#include <stdint.h>

// Match numpy semantics: no FMA contraction anywhere in decision-critical math.
#pragma clang fp contract(off)

#define N_ANCHORS 172032  // compile-time problem constant
#define MAX_OUT 200
#define CAP2 65536        // full candidate set (~59,282 expected; +31 sigma margin)
#define BLK 1024
#define NW (BLK / 64)

typedef unsigned long long ull;

// f64 decode: f32 inputs upcast to f64, reference op order.
// Returns (y1,x1,y2,x2).
__device__ __forceinline__ void decode_box_d(const float4* __restrict__ reg,
                                             const float4* __restrict__ anc, int i,
                                             double b[4]) {
#pragma clang fp contract(off)
    float4 r = reg[i];
    float4 a = anc[i];
    double dx = (double)r.x * 0.1;
    double dy = (double)r.y * 0.1;
    double dw = (double)r.z * 0.2;
    double dh = (double)r.w * 0.2;
    double xa = (double)a.x, ya = (double)a.y, wa = (double)a.z, ha = (double)a.w;
    double xc = dx * wa; xc = xc + xa;     // dx*w_a + x_a
    double yc = dy * ha; yc = yc + ya;     // dy*h_a + y_a
    double w = exp(dw) * wa;
    double h = exp(dh) * ha;
    double h2 = h * 0.5, w2 = w * 0.5;
    b[0] = yc - h2; b[1] = xc - w2; b[2] = yc + h2; b[3] = xc + w2;
}

__device__ __forceinline__ ull wmax(ull k) {
    for (int d = 32; d > 0; d >>= 1) {
        ull o = __shfl_down(k, d, 64);
        if (o > k) k = o;
    }
    return k;   // lane 0 holds the max
}

// ---------- kernel 1: compact ALL candidates (score>0.4) + pre-decoded boxes ----------
__global__ void k_compact2(const float2* __restrict__ cls,
                           const float4* __restrict__ reg,
                           const float4* __restrict__ anc, int n,
                           int* __restrict__ ctr,
                           ull* __restrict__ keys, float4* __restrict__ boxes) {
    int i = blockIdx.x * blockDim.x + threadIdx.x;
    if (i >= n) return;
    float sc = cls[i].y;                       // score = cls[:,1]
    if ((double)sc > 0.4) {
        int pos = atomicAdd(&ctr[0], 1);
        if (pos < CAP2) {
            keys[pos] = ((ull)__float_as_uint(sc) << 32)
                      | (ull)(0xFFFFFFFFu - (unsigned int)i);
            double b[4];
            decode_box_d(reg, anc, i, b);
            boxes[pos] = make_float4((float)b[0], (float)b[1], (float)b[2], (float)b[3]);
        }
    }
}

// ---------- kernel 2: literal greedy NMS (argmax + suppress), full candidate set ----------
__global__ void __launch_bounds__(BLK) k_nms_lit(int* __restrict__ ctr,
                                                 ull* __restrict__ keys,
                                                 const float4* __restrict__ boxes,
                                                 int* __restrict__ kept) {
    __shared__ ull warr[NW];
    __shared__ ull s_win;
    __shared__ double s_pb[5];        // y1,x1,y2,x2,area of current pick
    __shared__ int kidx[MAX_OUT];

    int tid = threadIdx.x;
    int C = ctr[0]; if (C > CAP2) C = CAP2;

    int ln = 0;
    for (int out = 0; out < MAX_OUT; ++out) {
        // argmax over alive keys (dead == 0); key = (score_bits<<32)|~idx => np.argmax
        // first-max tie-break (smallest index wins among equal scores)
        ull k = 0;
        for (int j = tid; j < C; j += BLK) { ull kk = keys[j]; if (kk > k) k = kk; }
        k = wmax(k);
        if ((tid & 63) == 0) warr[tid >> 6] = k;
        __syncthreads();
        if (tid < 64) {
            ull v = (tid < NW) ? warr[tid] : 0ull;
            v = wmax(v);
            if (tid == 0) s_win = v;
        }
        __syncthreads();
        ull win = s_win;
        if (win == 0ull) break;                       // all suppressed
        // locate winner (keys unique), record pick, kill it
        for (int j = tid; j < C; j += BLK) {
            if (keys[j] == win) {
                float4 b = boxes[j];
                s_pb[0] = (double)b.x; s_pb[1] = (double)b.y;
                s_pb[2] = (double)b.z; s_pb[3] = (double)b.w;
                s_pb[4] = ((double)b.z - (double)b.x) * ((double)b.w - (double)b.y);
                kidx[out] = (int)(0xFFFFFFFFu - (unsigned int)win);
                keys[j] = 0ull;
            }
        }
        __syncthreads();
        double p0 = s_pb[0], p1 = s_pb[1], p2 = s_pb[2], p3 = s_pb[3], pa = s_pb[4];
        for (int j = tid; j < C; j += BLK) {
            if (keys[j] != 0ull) {
                float4 b = boxes[j];
                double y1 = (double)b.x, x1 = (double)b.y, y2 = (double)b.z, x2 = (double)b.w;
                double ih = fmin(y2, p2) - fmax(y1, p0); ih = fmax(ih, 0.0);
                double iw = fmin(x2, p3) - fmax(x1, p1); iw = fmax(iw, 0.0);
                double inter = ih * iw;
                double aa = (y2 - y1) * (x2 - x1);
                double den = aa + pa; den = den - inter; den = den + 1e-12;
                if (inter / den > 0.4) keys[j] = 0ull;
            }
        }
        __syncthreads();
        ln = out + 1;
    }
    __syncthreads();
    for (int q = tid; q < MAX_OUT; q += BLK) kept[q] = (q < ln) ? kidx[q] : -1;
}

// ---------- kernel 3: gather + f64 decode outputs, write FLOAT32 ----------
// Output = reference's f32 tuple, flat: boxes (200,4) then landmarks (200,10).
__global__ void k_out(const float4* __restrict__ reg, const float4* __restrict__ anc,
                      const float* __restrict__ lnd,
                      const int* __restrict__ kept, float* __restrict__ out) {
#pragma clang fp contract(off)
    int q = threadIdx.x;
    if (q >= MAX_OUT) return;
    int idx = kept[q];
    float b[4] = {0.f, 0.f, 0.f, 0.f};
    float l10[10] = {0.f, 0.f, 0.f, 0.f, 0.f, 0.f, 0.f, 0.f, 0.f, 0.f};
    if (idx >= 0) {
        double bb[4];
        decode_box_d(reg, anc, idx, bb);
        b[0] = (float)bb[0]; b[1] = (float)bb[1]; b[2] = (float)bb[2]; b[3] = (float)bb[3];
        float4 a = anc[idx];
        double xa = (double)a.x, ya = (double)a.y, wa = (double)a.z, ha = (double)a.w;
        for (int j = 0; j < 5; ++j) {
            double lx = (double)lnd[idx * 10 + 2 * j]     * 0.1;
            double ly = (double)lnd[idx * 10 + 2 * j + 1] * 0.1;
            lx = lx * wa; lx = lx + xa;
            ly = ly * ha; ly = ly + ya;
            l10[2 * j] = (float)lx; l10[2 * j + 1] = (float)ly;
        }
    }
    for (int c = 0; c < 4; ++c)  out[q * 4 + c] = b[c];
    for (int c = 0; c < 10; ++c) out[MAX_OUT * 4 + q * 10 + c] = l10[c];
}

extern "C" void kernel_launch(void* const* d_in, const int* in_sizes, int n_in,
                              void* d_out, int out_size, void* d_ws, size_t ws_size,
                              hipStream_t stream) {
    // Dict order verified by content fingerprint (round 6): d_in[3] = anchors.
    const float2* cls = (const float2*)d_in[0];    // (N,2) f32
    const float4* reg = (const float4*)d_in[1];    // (N,4) f32
    const float*  lnd = (const float*)d_in[2];     // (N,10) f32
    const float4* anc = (const float4*)d_in[3];    // (N,4) f32
    const int n = N_ANCHORS;

    uint8_t* w = (uint8_t*)d_ws;
    ull*    keys  = (ull*)w;                        // 65536*8  = 524288 B
    float4* boxes = (float4*)(w + 524288);          // 65536*16 = 1048576 B
    int*    ctr   = (int*)(w + 1572864);            // 64 B
    int*    kept  = (int*)(w + 1572928);            // 1024 B

    hipMemsetAsync(w + 1572864, 0, 64, stream);
    int grid = (n + 255) / 256;
    k_compact2<<<grid, 256, 0, stream>>>(cls, reg, anc, n, ctr, keys, boxes);
    k_nms_lit<<<1, BLK, 0, stream>>>(ctr, keys, boxes, kept);
    k_out<<<1, 256, 0, stream>>>(reg, anc, lnd, kept, (float*)d_out);
}

// Round 11
// 353.900 us; speedup vs baseline: 23.0883x; 23.0883x over previous
//
#include <hip/hip_runtime.h>
#include <stdint.h>

// Match numpy semantics: no FMA contraction anywhere in decision-critical math.
#pragma clang fp contract(off)

#define N_ANCHORS 172032  // compile-time problem constant
#define MAX_OUT 200
#define KTOP 2048         // top-K prefix (round-5 evidence: top-1024 suffices for 200 keeps)
#define KW (KTOP / 64)    // 32 bitmask words per row
#define TARGET 1600       // threshold target (csel ~1600-1700 << KTOP)
#define CAP2 65536        // full candidate set capacity (fallback path)
#define NBINS 65536
#define BLK 1024
#define NW (BLK / 64)

typedef unsigned long long ull;

// f64 decode: f32 inputs upcast to f64, reference op order. Returns (y1,x1,y2,x2).
__device__ __forceinline__ void decode_box_d(const float4* __restrict__ reg,
                                             const float4* __restrict__ anc, int i,
                                             double b[4]) {
#pragma clang fp contract(off)
    float4 r = reg[i];
    float4 a = anc[i];
    double dx = (double)r.x * 0.1;
    double dy = (double)r.y * 0.1;
    double dw = (double)r.z * 0.2;
    double dh = (double)r.w * 0.2;
    double xa = (double)a.x, ya = (double)a.y, wa = (double)a.z, ha = (double)a.w;
    double xc = dx * wa; xc = xc + xa;     // dx*w_a + x_a
    double yc = dy * ha; yc = yc + ya;     // dy*h_a + y_a
    double w = exp(dw) * wa;
    double h = exp(dh) * ha;
    double h2 = h * 0.5, w2 = w * 0.5;
    b[0] = yc - h2; b[1] = xc - w2; b[2] = yc + h2; b[3] = xc + w2;
}

__device__ __forceinline__ ull wmax(ull k) {
    for (int d = 32; d > 0; d >>= 1) {
        ull o = __shfl_down(k, d, 64);
        if (o > k) k = o;
    }
    return k;
}

// ---------- kernel 1: histogram of score top-16 bits ----------
__global__ void k_hist(const float2* __restrict__ cls, int n, int* __restrict__ hist) {
    int i = blockIdx.x * blockDim.x + threadIdx.x;
    if (i >= n) return;
    float sc = cls[i].y;
    if ((double)sc > 0.4) atomicAdd(&hist[__float_as_uint(sc) >> 16], 1);
}

// ---------- kernel 2: pick score-bits threshold for ~TARGET top candidates ----------
__global__ void k_thresh(const int* __restrict__ hist, int* __restrict__ ctr) {
    __shared__ int cs[BLK];
    int tid = threadIdx.x;
    int sum = 0;
    int base = tid * (NBINS / BLK);
    for (int j = 0; j < NBINS / BLK; ++j) sum += hist[base + j];
    cs[tid] = sum;
    __syncthreads();
    if (tid == 0) {
        long long total = 0;
        for (int c = 0; c < BLK; ++c) total += cs[c];
        int Tbin = 0;
        if (total >= TARGET) {
            long long cum = 0;
            int c = BLK - 1;
            for (; c >= 0; --c) { if (cum + cs[c] >= TARGET) break; cum += cs[c]; }
            int b = c * (NBINS / BLK) + (NBINS / BLK) - 1;
            for (;; --b) { cum += hist[b]; if (cum >= TARGET) break; }
            Tbin = b;
        }
        ctr[1] = Tbin << 16;      // f32-bit threshold (positive scores -> monotone)
        ctr[3] = (int)total;      // total candidates
    }
}

// ---------- kernel 3: compact full set (fallback) + top-K subset ----------
__global__ void k_compact3(const float2* __restrict__ cls,
                           const float4* __restrict__ reg,
                           const float4* __restrict__ anc, int n,
                           int* __restrict__ ctr,
                           ull* __restrict__ keys_full, float4* __restrict__ boxes_full,
                           ull* __restrict__ keys_top) {
    int i = blockIdx.x * blockDim.x + threadIdx.x;
    if (i >= n) return;
    float sc = cls[i].y;
    if ((double)sc > 0.4) {
        unsigned int bits = __float_as_uint(sc);
        ull key = ((ull)bits << 32) | (ull)(0xFFFFFFFFu - (unsigned int)i);
        int pos = atomicAdd(&ctr[0], 1);
        if (pos < CAP2) {
            keys_full[pos] = key;
            double b[4];
            decode_box_d(reg, anc, i, b);
            boxes_full[pos] = make_float4((float)b[0], (float)b[1], (float)b[2], (float)b[3]);
        }
        if (bits >= (unsigned int)ctr[1]) {
            int p2 = atomicAdd(&ctr[5], 1);
            if (p2 < KTOP) keys_top[p2] = key;
        }
    }
}

// ---------- kernel 4: bitonic sort top-K (desc), emit sidx + decoded boxes ----------
__global__ void __launch_bounds__(BLK) k_sort(const float4* __restrict__ reg,
                                              const float4* __restrict__ anc,
                                              const int* __restrict__ ctr,
                                              const ull* __restrict__ keys_top,
                                              int* __restrict__ sidx,
                                              float4* __restrict__ bsort) {
    __shared__ ull sk[KTOP];      // 16 KB
    int tid = threadIdx.x;
    int csel = ctr[5];
    int C2 = (csel > KTOP) ? KTOP : csel;
    for (int j = tid; j < KTOP; j += BLK) sk[j] = (j < C2) ? keys_top[j] : 0ull;
    __syncthreads();
    // descending: score desc, idx asc (via complemented idx) — validated round 2
    for (int k = 2; k <= KTOP; k <<= 1) {
        for (int j = k >> 1; j > 0; j >>= 1) {
            for (int i = tid; i < KTOP; i += BLK) {
                int l = i ^ j;
                if (l > i) {
                    bool desc = ((i & k) == 0);
                    ull a = sk[i], b = sk[l];
                    if (desc ? (a < b) : (a > b)) { sk[i] = b; sk[l] = a; }
                }
            }
            __syncthreads();
        }
    }
    for (int r = tid; r < KTOP; r += BLK) {
        if (r < C2) {
            int idx = (int)(0xFFFFFFFFu - (unsigned int)sk[r]);
            sidx[r] = idx;
            double b[4];
            decode_box_d(reg, anc, idx, b);
            bsort[r] = make_float4((float)b[0], (float)b[1], (float)b[2], (float)b[3]);
        } else {
            sidx[r] = -1;
            bsort[r] = make_float4(0.f, 0.f, 0.f, 0.f);  // zero-area: IoU vs anything = 0
        }
    }
}

// ---------- kernel 5: suppression bit-matrix (i suppresses j, j>i) ----------
__global__ void k_iou(const float4* __restrict__ bsort, ull* __restrict__ mat) {
#pragma clang fp contract(off)
    int t = blockIdx.x * blockDim.x + threadIdx.x;   // KTOP*KW threads
    int i = t >> 5;                                  // row (pick rank)
    int w = t & (KW - 1);                            // 64-col word
    float4 bi = bsort[i];
    double p0 = (double)bi.x, p1 = (double)bi.y, p2 = (double)bi.z, p3 = (double)bi.w;
    double ai = (p2 - p0) * (p3 - p1);
    ull bits = 0;
    int jbase = w << 6;
    for (int b = 0; b < 64; ++b) {
        int j = jbase + b;
        if (j > i) {
            float4 bj = bsort[j];
            double y1 = (double)bj.x, x1 = (double)bj.y, y2 = (double)bj.z, x2 = (double)bj.w;
            double ih = fmin(y2, p2) - fmax(y1, p0); ih = fmax(ih, 0.0);
            double iw = fmin(x2, p3) - fmax(x1, p1); iw = fmax(iw, 0.0);
            double inter = ih * iw;
            double aj = (y2 - y1) * (x2 - x1);
            double den = aj + ai; den = den - inter; den = den + 1e-12;
            if (inter / den > 0.4) bits |= (1ull << b);
        }
    }
    mat[(size_t)i * KW + w] = bits;
}

// ---------- kernel 6: single-wave sequential greedy scan over the bit-matrix ----------
__global__ void k_scan(const int* __restrict__ ctr, const int* __restrict__ sidx,
                       const ull* __restrict__ mat,
                       int* __restrict__ kept, int* __restrict__ flag) {
    __shared__ ull removed[KW];
    __shared__ int s_k[MAX_OUT];
    int lane = threadIdx.x;       // 64 threads = 1 wave
    int csel = ctr[5];
    int total = ctr[3];
    if (csel > KTOP) { if (lane == 0) *flag = 1; return; }   // overflow -> fallback
    int C2 = csel;
    if (lane < KW) removed[lane] = 0ull;
    __syncthreads();
    int ln = 0;
    for (int w = 0; w < KW && ln < MAX_OUT; ++w) {
        int base = w << 6;
        if (base >= C2) break;
        int nb = C2 - base;
        ull vmask = (nb >= 64) ? ~0ull : ((1ull << nb) - 1ull);
        ull cur = removed[w];
        __syncthreads();
        ull avail = ~cur & vmask;
        while (avail && ln < MAX_OUT) {
            int b = __ffsll(avail) - 1;
            int r = base + b;
            if (lane == 0) s_k[ln] = sidx[r];
            ln++;
            if (lane < KW) removed[lane] |= mat[(size_t)r * KW + lane];
            __syncthreads();
            cur = removed[w];
            __syncthreads();
            ull gt = (b == 63) ? 0ull : (~0ull << (b + 1));
            avail = ~cur & vmask & gt;
        }
    }
    __syncthreads();
    bool need_full = (ln < MAX_OUT && total > csel);
    if (lane == 0) *flag = need_full ? 1 : 0;
    if (!need_full)
        for (int q = lane; q < MAX_OUT; q += 64) kept[q] = (q < ln) ? s_k[q] : -1;
}

// ---------- kernel 7: fallback literal machine (round-10, flag-gated) ----------
__global__ void __launch_bounds__(BLK) k_nms_lit(int* __restrict__ ctr,
                                                 ull* __restrict__ keys,
                                                 const float4* __restrict__ boxes,
                                                 const int* __restrict__ flag,
                                                 int* __restrict__ kept) {
    if (*flag == 0) return;                         // prefix sufficed (expected path)
    __shared__ ull warr[NW];
    __shared__ ull s_win;
    __shared__ double s_pb[5];
    __shared__ int kidx[MAX_OUT];
    int tid = threadIdx.x;
    int C = ctr[0]; if (C > CAP2) C = CAP2;
    int ln = 0;
    for (int out = 0; out < MAX_OUT; ++out) {
        ull k = 0;
        for (int j = tid; j < C; j += BLK) { ull kk = keys[j]; if (kk > k) k = kk; }
        k = wmax(k);
        if ((tid & 63) == 0) warr[tid >> 6] = k;
        __syncthreads();
        if (tid < 64) {
            ull v = (tid < NW) ? warr[tid] : 0ull;
            v = wmax(v);
            if (tid == 0) s_win = v;
        }
        __syncthreads();
        ull win = s_win;
        if (win == 0ull) break;
        for (int j = tid; j < C; j += BLK) {
            if (keys[j] == win) {
                float4 b = boxes[j];
                s_pb[0] = (double)b.x; s_pb[1] = (double)b.y;
                s_pb[2] = (double)b.z; s_pb[3] = (double)b.w;
                s_pb[4] = ((double)b.z - (double)b.x) * ((double)b.w - (double)b.y);
                kidx[out] = (int)(0xFFFFFFFFu - (unsigned int)win);
                keys[j] = 0ull;
            }
        }
        __syncthreads();
        double p0 = s_pb[0], p1 = s_pb[1], p2 = s_pb[2], p3 = s_pb[3], pa = s_pb[4];
        for (int j = tid; j < C; j += BLK) {
            if (keys[j] != 0ull) {
                float4 b = boxes[j];
                double y1 = (double)b.x, x1 = (double)b.y, y2 = (double)b.z, x2 = (double)b.w;
                double ih = fmin(y2, p2) - fmax(y1, p0); ih = fmax(ih, 0.0);
                double iw = fmin(x2, p3) - fmax(x1, p1); iw = fmax(iw, 0.0);
                double inter = ih * iw;
                double aa = (y2 - y1) * (x2 - x1);
                double den = aa + pa; den = den - inter; den = den + 1e-12;
                if (inter / den > 0.4) keys[j] = 0ull;
            }
        }
        __syncthreads();
        ln = out + 1;
    }
    __syncthreads();
    for (int q = tid; q < MAX_OUT; q += BLK) kept[q] = (q < ln) ? kidx[q] : -1;
}

// ---------- kernel 8: gather + f64 decode outputs, write f32 ----------
__global__ void k_out(const float4* __restrict__ reg, const float4* __restrict__ anc,
                      const float* __restrict__ lnd,
                      const int* __restrict__ kept, float* __restrict__ out) {
#pragma clang fp contract(off)
    int q = threadIdx.x;
    if (q >= MAX_OUT) return;
    int idx = kept[q];
    float b[4] = {0.f, 0.f, 0.f, 0.f};
    float l10[10] = {0.f, 0.f, 0.f, 0.f, 0.f, 0.f, 0.f, 0.f, 0.f, 0.f};
    if (idx >= 0) {
        double bb[4];
        decode_box_d(reg, anc, idx, bb);
        b[0] = (float)bb[0]; b[1] = (float)bb[1]; b[2] = (float)bb[2]; b[3] = (float)bb[3];
        float4 a = anc[idx];
        double xa = (double)a.x, ya = (double)a.y, wa = (double)a.z, ha = (double)a.w;
        for (int j = 0; j < 5; ++j) {
            double lx = (double)lnd[idx * 10 + 2 * j]     * 0.1;
            double ly = (double)lnd[idx * 10 + 2 * j + 1] * 0.1;
            lx = lx * wa; lx = lx + xa;
            ly = ly * ha; ly = ly + ya;
            l10[2 * j] = (float)lx; l10[2 * j + 1] = (float)ly;
        }
    }
    for (int c = 0; c < 4; ++c)  out[q * 4 + c] = b[c];
    for (int c = 0; c < 10; ++c) out[MAX_OUT * 4 + q * 10 + c] = l10[c];
}

extern "C" void kernel_launch(void* const* d_in, const int* in_sizes, int n_in,
                              void* d_out, int out_size, void* d_ws, size_t ws_size,
                              hipStream_t stream) {
    const float2* cls = (const float2*)d_in[0];    // (N,2) f32
    const float4* reg = (const float4*)d_in[1];    // (N,4) f32
    const float*  lnd = (const float*)d_in[2];     // (N,10) f32
    const float4* anc = (const float4*)d_in[3];    // (N,4) f32
    const int n = N_ANCHORS;

    uint8_t* w = (uint8_t*)d_ws;
    int*    hist       = (int*)w;                       //       0: 262144 B
    int*    ctr        = (int*)(w + 262144);            //  262144: 64 B
    int*    flag       = (int*)(w + 262208);            //  262208: 64 B
    int*    kept       = (int*)(w + 262272);            //  262272: 1024 B
    ull*    keys_top   = (ull*)(w + 263296);            //  263296: 16384 B
    int*    sidx       = (int*)(w + 279680);            //  279680: 8192 B
    float4* bsort      = (float4*)(w + 287872);         //  287872: 32768 B
    ull*    mat        = (ull*)(w + 320640);            //  320640: 524288 B
    ull*    keys_full  = (ull*)(w + 844928);            //  844928: 524288 B
    float4* boxes_full = (float4*)(w + 1369216);        // 1369216: 1048576 B

    hipMemsetAsync(w, 0, 263296, stream);               // hist + ctr + flag + kept
    int grid = (n + 255) / 256;
    k_hist<<<grid, 256, 0, stream>>>(cls, n, hist);
    k_thresh<<<1, BLK, 0, stream>>>(hist, ctr);
    k_compact3<<<grid, 256, 0, stream>>>(cls, reg, anc, n, ctr, keys_full, boxes_full, keys_top);
    k_sort<<<1, BLK, 0, stream>>>(reg, anc, ctr, keys_top, sidx, bsort);
    k_iou<<<(KTOP * KW) / 256, 256, 0, stream>>>(bsort, mat);
    k_scan<<<1, 64, 0, stream>>>(ctr, sidx, mat, kept, flag);
    k_nms_lit<<<1, BLK, 0, stream>>>(ctr, keys_full, boxes_full, flag, kept);
    k_out<<<1, 256, 0, stream>>>(reg, anc, lnd, kept, (float*)d_out);
}

// Round 12
// 335.358 us; speedup vs baseline: 24.3649x; 1.0553x over previous
//
#include <hip/hip_runtime.h>
#include <stdint.h>

// Match numpy semantics: no FMA contraction anywhere in decision-critical math.
#pragma clang fp contract(off)

#define N_ANCHORS 172032  // compile-time problem constant
#define MAX_OUT 200
#define KTOP 2048         // top-K prefix capacity
#define KWU (KTOP / 32)   // 64 removed-mask words
#define BLK 1024
#define NW (BLK / 64)
#define VT 2.35f          // fixed top threshold: scores ~ N(0,1) exactly =>
                          // csel = 172032*P(N>2.35) ~ 1615 +/- 40 (5sig < 2048).
                          // rank_200 <= ~905 (round-5 evidence). Fallback guards both.

typedef unsigned long long ull;

// f64 decode: f32 inputs upcast to f64, reference op order. Returns (y1,x1,y2,x2).
__device__ __forceinline__ void decode_box_d(const float4* __restrict__ reg,
                                             const float4* __restrict__ anc, int i,
                                             double b[4]) {
#pragma clang fp contract(off)
    float4 r = reg[i];
    float4 a = anc[i];
    double dx = (double)r.x * 0.1;
    double dy = (double)r.y * 0.1;
    double dw = (double)r.z * 0.2;
    double dh = (double)r.w * 0.2;
    double xa = (double)a.x, ya = (double)a.y, wa = (double)a.z, ha = (double)a.w;
    double xc = dx * wa; xc = xc + xa;     // dx*w_a + x_a
    double yc = dy * ha; yc = yc + ya;     // dy*h_a + y_a
    double w = exp(dw) * wa;
    double h = exp(dh) * ha;
    double h2 = h * 0.5, w2 = w * 0.5;
    b[0] = yc - h2; b[1] = xc - w2; b[2] = yc + h2; b[3] = xc + w2;
}

// Gather + f64 decode one output row (boxes + landmarks), write f32.
__device__ __forceinline__ void write_row(const float4* __restrict__ reg,
                                          const float4* __restrict__ anc,
                                          const float* __restrict__ lnd,
                                          int q, int idx, float* __restrict__ out) {
#pragma clang fp contract(off)
    float b[4] = {0.f, 0.f, 0.f, 0.f};
    float l10[10] = {0.f, 0.f, 0.f, 0.f, 0.f, 0.f, 0.f, 0.f, 0.f, 0.f};
    if (idx >= 0) {
        double bb[4];
        decode_box_d(reg, anc, idx, bb);
        b[0] = (float)bb[0]; b[1] = (float)bb[1]; b[2] = (float)bb[2]; b[3] = (float)bb[3];
        float4 a = anc[idx];
        double xa = (double)a.x, ya = (double)a.y, wa = (double)a.z, ha = (double)a.w;
        for (int j = 0; j < 5; ++j) {
            double lx = (double)lnd[idx * 10 + 2 * j]     * 0.1;
            double ly = (double)lnd[idx * 10 + 2 * j + 1] * 0.1;
            lx = lx * wa; lx = lx + xa;
            ly = ly * ha; ly = ly + ya;
            l10[2 * j] = (float)lx; l10[2 * j + 1] = (float)ly;
        }
    }
    for (int c = 0; c < 4; ++c)  out[q * 4 + c] = b[c];
    for (int c = 0; c < 10; ++c) out[MAX_OUT * 4 + q * 10 + c] = l10[c];
}

__device__ __forceinline__ ull wmax(ull k) {
    for (int d = 32; d > 0; d >>= 1) {
        ull o = __shfl_down(k, d, 64);
        if (o > k) k = o;
    }
    return k;
}

// ---------- kernel 1: compact top candidates (fixed threshold) + total count ----------
__global__ void k_compact_top(const float2* __restrict__ cls, int n,
                              int* __restrict__ ctr, ull* __restrict__ keys) {
    int i = blockIdx.x * blockDim.x + threadIdx.x;
    if (i >= n) return;
    float sc = cls[i].y;                       // score = cls[:,1]
    if ((double)sc > 0.4) {
        atomicAdd(&ctr[3], 1);                 // total candidates (exhaustion guard)
        if (sc > VT) {
            int pos = atomicAdd(&ctr[0], 1);
            if (pos < KTOP)
                keys[pos] = ((ull)__float_as_uint(sc) << 32)
                          | (ull)(0xFFFFFFFFu - (unsigned int)i);
        }
    }
}

// ---------- kernel 2: fused sort + greedy NMS (LDS-resident) + output ----------
__global__ void __launch_bounds__(BLK) k_fused(const float4* __restrict__ reg,
                                               const float4* __restrict__ anc,
                                               const float* __restrict__ lnd,
                                               const int* __restrict__ ctr,
                                               const ull* __restrict__ gkeys,
                                               int* __restrict__ flag,
                                               float* __restrict__ out) {
    __shared__ ull sk[KTOP];               // 16 KB
    __shared__ float4 sbox[KTOP];          // 32 KB
    __shared__ int ssidx[KTOP];            // 8 KB
    __shared__ unsigned int removed[KWU];  // 256 B
    __shared__ int s_kept[MAX_OUT];
    __shared__ int s_r;

    int tid = threadIdx.x;
    int csel  = ctr[0];
    int total = ctr[3];
    if (csel > KTOP) { if (tid == 0) *flag = 1; return; }   // overflow -> fallback

    for (int j = tid; j < KTOP; j += BLK) sk[j] = (j < csel) ? gkeys[j] : 0ull;
    __syncthreads();

    // bitonic sort desc (score desc, idx asc via ~idx) — validated rounds 2/11
    for (int k = 2; k <= KTOP; k <<= 1) {
        for (int j = k >> 1; j > 0; j >>= 1) {
            for (int i = tid; i < KTOP; i += BLK) {
                int l = i ^ j;
                if (l > i) {
                    bool desc = ((i & k) == 0);
                    ull a = sk[i], b = sk[l];
                    if (desc ? (a < b) : (a > b)) { sk[i] = b; sk[l] = a; }
                }
            }
            __syncthreads();
        }
    }

    // decode boxes into LDS; init removed mask (ranks >= csel pre-removed)
    for (int r = tid; r < KTOP; r += BLK) {
        if (r < csel) {
            int idx = (int)(0xFFFFFFFFu - (unsigned int)sk[r]);
            ssidx[r] = idx;
            double b[4];
            decode_box_d(reg, anc, idx, b);
            sbox[r] = make_float4((float)b[0], (float)b[1], (float)b[2], (float)b[3]);
        } else {
            ssidx[r] = -1;
            sbox[r] = make_float4(0.f, 0.f, 0.f, 0.f);
        }
    }
    for (int w = tid; w < KWU; w += BLK) {
        int base = w << 5;
        unsigned int m;
        if (base >= csel) m = 0xFFFFFFFFu;
        else if (base + 32 > csel) m = ~((1u << (csel - base)) - 1u);
        else m = 0u;
        removed[w] = m;
    }

    // greedy: pick = first alive rank (sorted order => no argmax needed);
    // suppress on the fly (2 f64 IoUs per thread per pick), all state in LDS.
    int ln = 0;
    int curw = 0;                           // tid0's monotone word cursor
    for (;;) {
        __syncthreads();                    // removed[] state stable
        if (tid == 0) {
            int r = -1;
            for (int w = curw; w < KWU; ++w) {
                unsigned int avail = ~removed[w];
                if (avail) { curw = w; r = (w << 5) + __ffs(avail) - 1; break; }
            }
            s_r = r;
            if (r >= 0) s_kept[ln] = ssidx[r];
        }
        __syncthreads();
        int r = s_r;
        if (r < 0) break;
        float4 pb = sbox[r];
        double p0 = (double)pb.x, p1 = (double)pb.y, p2 = (double)pb.z, p3 = (double)pb.w;
        double pa = (p2 - p0) * (p3 - p1);
        for (int k2 = tid; k2 < KTOP; k2 += BLK) {
            if (!((removed[k2 >> 5] >> (k2 & 31)) & 1u)) {
                float4 bj = sbox[k2];
                double y1 = (double)bj.x, x1 = (double)bj.y, y2 = (double)bj.z, x2 = (double)bj.w;
                double ih = fmin(y2, p2) - fmax(y1, p0); ih = fmax(ih, 0.0);
                double iw = fmin(x2, p3) - fmax(x1, p1); iw = fmax(iw, 0.0);
                double inter = ih * iw;
                double aj = (y2 - y1) * (x2 - x1);
                double den = aj + pa; den = den - inter; den = den + 1e-12;
                if (inter / den > 0.4) atomicOr(&removed[k2 >> 5], 1u << (k2 & 31));
                // note: k2==r removes the pick itself (IoU ~ 1)
            }
        }
        ln++;
        if (ln >= MAX_OUT) break;
    }
    __syncthreads();

    bool need_full = (ln < MAX_OUT && total > csel);
    if (tid == 0) *flag = need_full ? 1 : 0;
    if (need_full) return;                  // k_slow takes over

    if (tid < MAX_OUT)
        write_row(reg, anc, lnd, tid, (tid < ln) ? s_kept[tid] : -1, out);
}

// ---------- kernel 3: exact self-contained fallback (flag-gated; never runs) ----------
__global__ void __launch_bounds__(BLK) k_slow(const float2* __restrict__ cls,
                                              const float4* __restrict__ reg,
                                              const float4* __restrict__ anc,
                                              const float* __restrict__ lnd, int n,
                                              const int* __restrict__ flag,
                                              float* __restrict__ sbuf,
                                              float* __restrict__ out) {
    if (*flag == 0) return;                 // expected path: exit immediately
    __shared__ ull warr[NW];
    __shared__ ull s_win;
    __shared__ double s_pb[5];
    __shared__ int kidx[MAX_OUT];
    int tid = threadIdx.x;
    for (int i = tid; i < n; i += BLK) {
        float sc = cls[i].y;
        sbuf[i] = ((double)sc > 0.4) ? sc : 0.0f;
    }
    __syncthreads();
    int ln = 0;
    for (int oi = 0; oi < MAX_OUT; ++oi) {
        ull k = 0;
        for (int i = tid; i < n; i += BLK) {
            ull kk = ((ull)__float_as_uint(sbuf[i]) << 32)
                   | (ull)(0xFFFFFFFFu - (unsigned int)i);
            if (kk > k) k = kk;
        }
        k = wmax(k);
        if ((tid & 63) == 0) warr[tid >> 6] = k;
        __syncthreads();
        if (tid < 64) {
            ull v = (tid < NW) ? warr[tid] : 0ull;
            v = wmax(v);
            if (tid == 0) s_win = v;
        }
        __syncthreads();
        ull win = s_win;
        if ((win >> 32) == 0u) break;
        int pidx = (int)(0xFFFFFFFFu - (unsigned int)win);
        if (tid == 0) {
            double b[4];
            decode_box_d(reg, anc, pidx, b);
            s_pb[0] = b[0]; s_pb[1] = b[1]; s_pb[2] = b[2]; s_pb[3] = b[3];
            s_pb[4] = (b[2] - b[0]) * (b[3] - b[1]);
            kidx[oi] = pidx;
        }
        __syncthreads();
        double p0 = s_pb[0], p1 = s_pb[1], p2 = s_pb[2], p3 = s_pb[3], pa = s_pb[4];
        for (int i = tid; i < n; i += BLK) {
            float v = sbuf[i];
            if (v != 0.0f) {
                double b[4];
                decode_box_d(reg, anc, i, b);
                double ih = fmin(b[2], p2) - fmax(b[0], p0); ih = fmax(ih, 0.0);
                double iw = fmin(b[3], p3) - fmax(b[1], p1); iw = fmax(iw, 0.0);
                double inter = ih * iw;
                double aa = (b[2] - b[0]) * (b[3] - b[1]);
                double den = aa + pa; den = den - inter; den = den + 1e-12;
                if (inter / den > 0.4) sbuf[i] = 0.0f;   // kills the pick too
            }
        }
        __syncthreads();
        ln = oi + 1;
    }
    __syncthreads();
    if (tid < MAX_OUT)
        write_row(reg, anc, lnd, tid, (tid < ln) ? kidx[tid] : -1, out);
}

extern "C" void kernel_launch(void* const* d_in, const int* in_sizes, int n_in,
                              void* d_out, int out_size, void* d_ws, size_t ws_size,
                              hipStream_t stream) {
    const float2* cls = (const float2*)d_in[0];    // (N,2) f32
    const float4* reg = (const float4*)d_in[1];    // (N,4) f32
    const float*  lnd = (const float*)d_in[2];     // (N,10) f32
    const float4* anc = (const float4*)d_in[3];    // (N,4) f32
    const int n = N_ANCHORS;

    uint8_t* w = (uint8_t*)d_ws;
    int*   ctr  = (int*)w;                 //     0: 64 B   (ctr[0]=csel, ctr[3]=total)
    int*   flag = (int*)(w + 64);          //    64: 64 B   (written by k_fused)
    ull*   keys = (ull*)(w + 128);         //   128: 16384 B
    float* sbuf = (float*)(w + 16512);     // 16512: N*4 B  (fallback only)

    hipMemsetAsync(ctr, 0, 64, stream);
    int grid = (n + 255) / 256;
    k_compact_top<<<grid, 256, 0, stream>>>(cls, n, ctr, keys);
    k_fused<<<1, BLK, 0, stream>>>(reg, anc, lnd, ctr, keys, flag, (float*)d_out);
    k_slow<<<1, BLK, 0, stream>>>(cls, reg, anc, lnd, n, flag, sbuf, (float*)d_out);
}